// Round 11
// baseline (58.706 us; speedup 1.0000x reference)
//
#include <hip/hip_runtime.h>

#define B 64
#define T 512
#define E 512
#define H 64
#define NEG_INF (-1e30f)

#define PBM 64        // proj block M tile (rows per block)
#define PN 192        // proj output cols (q|k|v)

// q pre-scale: H^-0.5 * log2(e)  (scores land in log2 domain; folded into Wq)
#define QSCALE 0.18033688011112043f
#define DEFER_THR 8.0f

using short8 = __attribute__((ext_vector_type(8))) short;
using f32x16 = __attribute__((ext_vector_type(16))) float;

__device__ __forceinline__ unsigned short f2bf(float f) {
    unsigned int u = __float_as_uint(f);
    u += 0x7fffu + ((u >> 16) & 1u);
    return (unsigned short)(u >> 16);
}
__device__ __forceinline__ unsigned int bfpack_tr(float lo, float hi) {
    return (__float_as_uint(hi) & 0xffff0000u) | (__float_as_uint(lo) >> 16);
}

// ---------------------------------------------------------------------------
// Kernel 0: one-time prep.
// Blocks 0..383: W -> B-FRAGMENT layout wfrag[f][lane][8], f=(c*4+ks)*6+ct:
//   lane (ko=lane>>5, r=lane&31) holds col ct*32+r, elems k=c*64+ks*16+ko*8+e.
//   Wq scaled by QSCALE here (linear: (aW)x == a(Wx)).
// Blocks 384..511: attn_mask -> bitmask words.
// ---------------------------------------------------------------------------
__global__ __launch_bounds__(256) void prep(
    const float* __restrict__ Wq, const float* __restrict__ Wk,
    const float* __restrict__ Wv, const int* __restrict__ am,
    unsigned short* __restrict__ wfrag, unsigned int* __restrict__ mbits)
{
    const int bid = blockIdx.x;
    if (bid < 384) {
        const int i  = bid * 256 + threadIdx.x;      // 0..98303
        const int f  = i >> 9;                       // fragment id 0..191
        const int le = i & 511;
        const int ln = le >> 3, e = le & 7;
        const int ko = ln >> 5, rr = ln & 31;
        const int c  = f / 24;
        const int ks = (f - c * 24) / 6;
        const int ct = f % 6;
        const int col = ct * 32 + rr;                // 0..191
        const int kk  = c * 64 + ks * 16 + ko * 8 + e;
        const int seg = col >> 6, hh = col & 63;
        const float* W = (seg == 0) ? Wq : (seg == 1) ? Wk : Wv;
        float v = W[(size_t)kk * H + hh];
        if (seg == 0) v *= QSCALE;
        wfrag[i] = f2bf(v);
    } else {
        const int i = (bid - 384) * 256 + threadIdx.x;
        const unsigned long long bal = __ballot(am[i] != 0);
        const int lane = threadIdx.x & 63;
        if (lane == 0)       mbits[i >> 5] = (unsigned int)bal;
        else if (lane == 32) mbits[i >> 5] = (unsigned int)(bal >> 32);
    }
}

// ---------------------------------------------------------------------------
// Kernel 1: projection GEMM, burst-staged.
// Phase 1: stage the block's ENTIRE x-tile (64 rows x 512 f32 -> bf16, 64KB
//   LDS) in one deep pipelined burst (256B/thread in flight).  Granule
//   rotation swizzle: 16B granule g of row r lands at slot (g+r)&63.
// Phase 2 (ONE barrier later): 96 MFMAs; A-frags via ds_read_b128, B-frags
//   straight from L2-resident wfrag (coalesced lane*16B).  No Ws LDS, no
//   per-chunk barriers.  Epilogue: fragment-layout scatter (as R10).
// ---------------------------------------------------------------------------
__global__ __launch_bounds__(256) void proj_gemm(
    const float* __restrict__ x,
    const unsigned short* __restrict__ wfrag,
    unsigned short* __restrict__ qfrag, unsigned short* __restrict__ kfrag,
    unsigned short* __restrict__ vfrag)
{
    __shared__ unsigned short Xs[PBM * 512];   // 64 KB

    const int tid  = threadIdx.x;
    const int wid  = tid >> 6;
    const int lane = tid & 63;
    const int hi   = lane >> 5;
    const int r    = lane & 31;
    const int row0 = blockIdx.x * PBM;

    // ---- phase 1: burst-stage x ----
    #pragma unroll
    for (int half = 0; half < 2; ++half) {
        float4 va[8], vb2[8];
        #pragma unroll
        for (int p = 0; p < 8; ++p) {
            const int i  = (half * 8 + p) * 256 + tid;   // granule index
            const int rr = i >> 6, g = i & 63;
            const float4* src = reinterpret_cast<const float4*>(
                &x[(size_t)(row0 + rr) * E + g * 8]);
            va[p]  = src[0];
            vb2[p] = src[1];
        }
        #pragma unroll
        for (int p = 0; p < 8; ++p) {
            const int i  = (half * 8 + p) * 256 + tid;
            const int rr = i >> 6, g = i & 63;
            union { unsigned short us[8]; short8 v; } pk;
            pk.us[0] = f2bf(va[p].x);  pk.us[1] = f2bf(va[p].y);
            pk.us[2] = f2bf(va[p].z);  pk.us[3] = f2bf(va[p].w);
            pk.us[4] = f2bf(vb2[p].x); pk.us[5] = f2bf(vb2[p].y);
            pk.us[6] = f2bf(vb2[p].z); pk.us[7] = f2bf(vb2[p].w);
            *reinterpret_cast<short8*>(
                (char*)Xs + rr * 1024 + ((g + rr) & 63) * 16) = pk.v;
        }
    }
    __syncthreads();

    // ---- phase 2: MFMA sweep, no barriers ----
    const int mrow = (wid >> 1) * 32 + r;      // A row this lane reads
    const int ctb  = (wid & 1) * 3;            // wave's first col-tile
    f32x16 acc[3] = {};

    #pragma unroll
    for (int c = 0; c < 8; ++c) {
        #pragma unroll
        for (int ks = 0; ks < 4; ++ks) {
            const int g = c * 8 + ks * 2 + hi;
            const short8 a = *reinterpret_cast<const short8*>(
                (const char*)Xs + mrow * 1024 + ((g + mrow) & 63) * 16);
            #pragma unroll
            for (int nt = 0; nt < 3; ++nt) {
                const int f = (c * 4 + ks) * 6 + ctb + nt;
                const short8 b = *reinterpret_cast<const short8*>(
                    wfrag + (size_t)f * 512 + lane * 8);
                acc[nt] = __builtin_amdgcn_mfma_f32_32x32x16_bf16(a, b, acc[nt], 0, 0, 0);
            }
        }
    }

    // ---- epilogue: scatter into fragment layouts (QSCALE already in Wq) ----
    #pragma unroll
    for (int nt = 0; nt < 3; ++nt) {
        const int gc  = (ctb + nt) * 32 + r;
        const int seg = gc >> 6;
        const int h   = gc & 63;
        #pragma unroll
        for (int reg = 0; reg < 16; ++reg) {
            const int drow = (reg & 3) + 8 * (reg >> 2) + 4 * hi;
            const int grow = row0 + (wid >> 1) * 32 + drow;
            const float val = acc[nt][reg];
            const int bb  = grow >> 9;
            const int key = grow & 511;
            const int blk = key >> 5;
            const int kk  = key & 31;
            if (seg == 0) {
                qfrag[(((size_t)bb * 16 + blk) * 4 + (h >> 4)) * 512
                      + (((h >> 3) & 1) * 32 + kk) * 8 + (h & 7)] = f2bf(val);
            } else if (seg == 1) {
                kfrag[(((size_t)bb * 16 + blk) * 4 + (h >> 4)) * 512
                      + (((h >> 3) & 1) * 32 + kk) * 8 + (h & 7)] = f2bf(val);
            } else {
                vfrag[(((size_t)bb * 16 + blk) * 4 + ((kk >> 4) * 2 + (h >> 5))) * 512
                      + (((kk >> 3) & 1) * 32 + (h & 31)) * 8 + (kk & 7)] = f2bf(val);
            }
        }
    }
}

// ---------------------------------------------------------------------------
// Kernel 2: ONLINE flash attention (unchanged from R10).
// ---------------------------------------------------------------------------
__global__ __launch_bounds__(64) void attn_online(
    const unsigned short* __restrict__ qfrag,
    const unsigned short* __restrict__ kfrag,
    const unsigned short* __restrict__ vfrag,
    const unsigned int* __restrict__ mbits,
    float* __restrict__ out)
{
    const int lane = threadIdx.x;
    const int hi = lane >> 5, r = lane & 31;
    const int h4 = 4 * hi;

    const int bid = blockIdx.x;
    const int k   = bid >> 3;
    const int b   = ((k >> 4) << 3) | (bid & 7);
    const int s   = 15 - (k & 15);
    const int t0  = s * 32;
    const int tq  = t0 + r;

    const int l8 = lane * 8;

    short8 qf[4];
    {
        const unsigned short* qb = qfrag + (((size_t)b * 16 + s) * 4) * 512;
        #pragma unroll
        for (int ks = 0; ks < 4; ++ks)
            qf[ks] = *reinterpret_cast<const short8*>(qb + ks * 512 + l8);
    }

    f32x16 accO[2] = {};
    float m = -INFINITY, l = 0.f;

    short8 kf[4], vb[4];
    {
        const unsigned short* kb = kfrag + ((size_t)b * 16) * 4 * 512;
        const unsigned short* vv = vfrag + ((size_t)b * 16) * 4 * 512;
        #pragma unroll
        for (int ks = 0; ks < 4; ++ks) {
            kf[ks] = *reinterpret_cast<const short8*>(kb + ks * 512 + l8);
            vb[ks] = *reinterpret_cast<const short8*>(vv + ks * 512 + l8);
        }
    }

    for (int j = 0; j <= s; ++j) {
        short8 kn[4], vn[4];
        if (j < s) {
            const unsigned short* kb = kfrag + (((size_t)b * 16 + j + 1) * 4) * 512;
            const unsigned short* vv = vfrag + (((size_t)b * 16 + j + 1) * 4) * 512;
            #pragma unroll
            for (int ks = 0; ks < 4; ++ks) {
                kn[ks] = *reinterpret_cast<const short8*>(kb + ks * 512 + l8);
                vn[ks] = *reinterpret_cast<const short8*>(vv + ks * 512 + l8);
            }
        }

        f32x16 sc = {};
        #pragma unroll
        for (int ks = 0; ks < 4; ++ks)
            sc = __builtin_amdgcn_mfma_f32_32x32x16_bf16(kf[ks], qf[ks], sc, 0, 0, 0);

        const unsigned int mw = mbits[b * 16 + j];
        float cmax = -INFINITY;
        if (j == s) {
            #pragma unroll
            for (int reg = 0; reg < 16; ++reg) {
                const int cr = (reg & 3) + 8 * (reg >> 2) + h4;
                float v = sc[reg];
                const bool bad = !((mw >> cr) & 1u) || (32 * j + cr > tq);
                v = bad ? NEG_INF : v;
                sc[reg] = v;
                cmax = fmaxf(cmax, v);
            }
        } else {
            #pragma unroll
            for (int reg = 0; reg < 16; ++reg) {
                const int cr = (reg & 3) + 8 * (reg >> 2) + h4;
                float v = sc[reg];
                v = ((mw >> cr) & 1u) ? v : NEG_INF;
                sc[reg] = v;
                cmax = fmaxf(cmax, v);
            }
        }
        cmax = fmaxf(cmax, __shfl_xor(cmax, 32));

        if (!__all(cmax <= m + DEFER_THR)) {
            const float m_new = fmaxf(m, cmax);
            const float scale = exp2f(m - m_new);
            f32x16 scf;
            #pragma unroll
            for (int reg = 0; reg < 16; ++reg)
                scf[reg] = __shfl(scale, (reg & 3) + 8 * (reg >> 2) + h4);
            #pragma unroll
            for (int reg = 0; reg < 16; ++reg) {
                accO[0][reg] *= scf[reg];
                accO[1][reg] *= scf[reg];
            }
            l *= scale;
            m = m_new;
        }

        float csum = 0.f;
        #pragma unroll
        for (int reg = 0; reg < 16; ++reg) {
            const float p = exp2f(sc[reg] - m);
            sc[reg] = p;
            csum += p;
        }
        csum += __shfl_xor(csum, 32);
        l += csum;

        unsigned int pk[8];
        #pragma unroll
        for (int jj = 0; jj < 8; ++jj)
            pk[jj] = bfpack_tr(sc[2 * jj], sc[2 * jj + 1]);
        #pragma unroll
        for (int hs = 0; hs < 2; ++hs) {
            const unsigned int p01 = pk[hs * 4 + 0], p23 = pk[hs * 4 + 1];
            const unsigned int p45 = pk[hs * 4 + 2], p67 = pk[hs * 4 + 3];
            const unsigned int sendA = hi ? p01 : p45;
            const unsigned int sendB = hi ? p23 : p67;
            const unsigned int recvA = (unsigned int)__shfl_xor((int)sendA, 32);
            const unsigned int recvB = (unsigned int)__shfl_xor((int)sendB, 32);
            union { unsigned int uu[4]; short8 s8; } aw;
            aw.uu[0] = hi ? recvA : p01;
            aw.uu[1] = hi ? recvB : p23;
            aw.uu[2] = hi ? p45 : recvA;
            aw.uu[3] = hi ? p67 : recvB;
            #pragma unroll
            for (int tile = 0; tile < 2; ++tile)
                accO[tile] = __builtin_amdgcn_mfma_f32_32x32x16_bf16(
                    aw.s8, vb[hs * 2 + tile], accO[tile], 0, 0, 0);
        }

        #pragma unroll
        for (int ks = 0; ks < 4; ++ks) { kf[ks] = kn[ks]; vb[ks] = vn[ks]; }
    }

    const float inv = 1.f / l;
    #pragma unroll
    for (int reg = 0; reg < 16; ++reg) {
        const int qrow = (reg & 3) + 8 * (reg >> 2) + h4;
        const float f = __shfl(inv, qrow);
        float* op = &out[((size_t)b * T + t0 + qrow) * H];
        op[r]      = accO[0][reg] * f;
        op[r + 32] = accO[1][reg] * f;
    }
}

// ---------------------------------------------------------------------------
extern "C" void kernel_launch(void* const* d_in, const int* in_sizes, int n_in,
                              void* d_out, int out_size, void* d_ws, size_t ws_size,
                              hipStream_t stream) {
    const float* x         = (const float*)d_in[0];
    const int*   attn_mask = (const int*)d_in[1];
    const float* Wk        = (const float*)d_in[2];
    const float* Wq        = (const float*)d_in[3];
    const float* Wv        = (const float*)d_in[4];
    float* out = (float*)d_out;

    unsigned short* qfrag = (unsigned short*)d_ws;                      // 4 MB
    unsigned short* kfrag = qfrag + (size_t)B * T * H;                  // 4 MB
    unsigned short* vfrag = kfrag + (size_t)B * T * H;                  // 4 MB
    unsigned short* wfrag = vfrag + (size_t)B * T * H;                  // 192 KB
    unsigned int*   mbits = (unsigned int*)(wfrag + (size_t)PN * E);    // 4 KB

    prep<<<512, 256, 0, stream>>>(Wq, Wk, Wv, attn_mask, wfrag, mbits);
    proj_gemm<<<(B * T) / PBM, 256, 0, stream>>>(x, wfrag, qfrag, kfrag, vfrag);
    attn_online<<<B * 16, 64, 0, stream>>>(qfrag, kfrag, vfrag, mbits, out);
}

// Round 12
// 48.133 us; speedup vs baseline: 1.2197x; 1.2197x over previous
//
#include <hip/hip_runtime.h>

#define B 64
#define T 512
#define E 512
#define H 64
#define NEG_INF (-1e30f)

// ---------------- projection GEMM params (R10, unchanged) ----------------
#define PBM 64
#define PBK 64
#define PN 192
#define NCHK (E / PBK)

// q pre-scale: H^-0.5 * log2(e)  (scores land in log2 domain)
#define QSCALE 0.18033688011112043f
#define DEFER_THR 8.0f

using short8 = __attribute__((ext_vector_type(8))) short;
using f32x16 = __attribute__((ext_vector_type(16))) float;

__device__ __forceinline__ unsigned short f2bf(float f) {
    unsigned int u = __float_as_uint(f);
    u += 0x7fffu + ((u >> 16) & 1u);
    return (unsigned short)(u >> 16);
}
__device__ __forceinline__ unsigned int bfpack_tr(float lo, float hi) {
    return (__float_as_uint(hi) & 0xffff0000u) | (__float_as_uint(lo) >> 16);
}
__device__ __forceinline__ void async_copy16(const void* g, void* l) {
    __builtin_amdgcn_global_load_lds(
        (const __attribute__((address_space(1))) unsigned int*)g,
        (__attribute__((address_space(3))) unsigned int*)l, 16, 0, 0);
}

// ---------------------------------------------------------------------------
// Kernel 0: one-time prep (R10, unchanged).
// ---------------------------------------------------------------------------
__global__ __launch_bounds__(256) void prep(
    const float* __restrict__ Wq, const float* __restrict__ Wk,
    const float* __restrict__ Wv, const int* __restrict__ am,
    unsigned short* __restrict__ WT_swz, unsigned int* __restrict__ mbits)
{
    const int bid = blockIdx.x;
    if (bid < 384) {
        const int i = bid * 256 + threadIdx.x;
        const int c   = i / (PN * 64);
        const int rem = i - c * (PN * 64);
        const int row = rem >> 6;
        const int s   = rem & 63;
        const int klocal = s ^ ((row & 7) << 3);
        const int k   = c * 64 + klocal;
        const int seg = row >> 6, hh = row & 63;
        const float* W = (seg == 0) ? Wq : (seg == 1) ? Wk : Wv;
        WT_swz[i] = f2bf(W[(size_t)k * H + hh]);
    } else {
        const int i = (bid - 384) * 256 + threadIdx.x;
        const unsigned long long bal = __ballot(am[i] != 0);
        const int lane = threadIdx.x & 63;
        if (lane == 0)       mbits[i >> 5] = (unsigned int)bal;
        else if (lane == 32) mbits[i >> 5] = (unsigned int)(bal >> 32);
    }
}

// ---------------------------------------------------------------------------
// Kernel 1: fused q/k/v projection GEMM, 2-phase dbuf (R10, unchanged),
// fragment-layout epilogue, QSCALE folded into q.
// ---------------------------------------------------------------------------
__global__ __launch_bounds__(256) void proj_gemm(
    const float* __restrict__ x,
    const unsigned short* __restrict__ WT_swz,
    unsigned short* __restrict__ qfrag, unsigned short* __restrict__ kfrag,
    unsigned short* __restrict__ vfrag)
{
    __shared__ unsigned short Xs[2][PBM * 64];
    __shared__ unsigned short Ws[2][PN * 64];

    const int tid  = threadIdx.x;
    const int wid  = tid >> 6;
    const int lane = tid & 63;
    const int hi   = lane >> 5;
    const int r    = lane & 31;
    const int row0 = blockIdx.x * PBM;

    const int mrow  = (wid >> 1) * 32 + r;
    const int cbase = (wid & 1) * 96;

    const int aBase = mrow * 128;
    const int aXor  = (mrow & 7) << 4;
    int bBase[3], bXor[3];
    #pragma unroll
    for (int nt = 0; nt < 3; ++nt) {
        const int col = cbase + nt * 32 + r;
        bBase[nt] = col * 128;
        bXor[nt]  = (col & 7) << 4;
    }
    const int xs_rr[2]  = { tid >> 3, (256 + tid) >> 3 };
    const int xs_s16[2] = { tid & 7, tid & 7 };

    f32x16 acc[3] = {};

    {
        #pragma unroll
        for (int p = 0; p < 6; ++p) {
            const int u = p * 256 + wid * 64 + lane;
            async_copy16(WT_swz + u * 8, (char*)(&Ws[0][0]) + (p * 256 + wid * 64) * 16);
        }
        #pragma unroll
        for (int p = 0; p < 2; ++p) {
            const int rr = xs_rr[p], s16 = xs_s16[p];
            const float4* src = reinterpret_cast<const float4*>(
                &x[(size_t)(row0 + rr) * E + s16 * 8]);
            const float4 a0 = src[0], a1 = src[1];
            union { unsigned short us[8]; short8 v; } pk;
            pk.us[0] = f2bf(a0.x); pk.us[1] = f2bf(a0.y);
            pk.us[2] = f2bf(a0.z); pk.us[3] = f2bf(a0.w);
            pk.us[4] = f2bf(a1.x); pk.us[5] = f2bf(a1.y);
            pk.us[6] = f2bf(a1.z); pk.us[7] = f2bf(a1.w);
            const int cb = (s16 * 16) ^ ((rr & 7) << 4);
            *reinterpret_cast<short8*>((char*)(&Xs[0][0]) + rr * 128 + cb) = pk.v;
        }
        __syncthreads();
    }

    for (int c = 0; c < NCHK; ++c) {
        const int cur = c & 1;
        const bool pre = (c + 1 < NCHK);
        float4 xa[2], xb[2];

        if (pre) {
            const unsigned short* gw = WT_swz + (size_t)(c + 1) * (PN * 64);
            #pragma unroll
            for (int p = 0; p < 6; ++p) {
                const int u = p * 256 + wid * 64 + lane;
                async_copy16(gw + u * 8,
                             (char*)(&Ws[cur ^ 1][0]) + (p * 256 + wid * 64) * 16);
            }
            const int kc = (c + 1) * PBK;
            #pragma unroll
            for (int p = 0; p < 2; ++p) {
                const float4* src = reinterpret_cast<const float4*>(
                    &x[(size_t)(row0 + xs_rr[p]) * E + kc + xs_s16[p] * 8]);
                xa[p] = src[0];
                xb[p] = src[1];
            }
        }

        #pragma unroll
        for (int ks = 0; ks < 4; ++ks) {
            const int koff = ks * 32 + hi * 16;
            const short8 a = *reinterpret_cast<const short8*>(
                (const char*)(&Xs[cur][0]) + aBase + (koff ^ aXor));
            #pragma unroll
            for (int nt = 0; nt < 3; ++nt) {
                const short8 b = *reinterpret_cast<const short8*>(
                    (const char*)(&Ws[cur][0]) + bBase[nt] + (koff ^ bXor[nt]));
                acc[nt] = __builtin_amdgcn_mfma_f32_32x32x16_bf16(a, b, acc[nt], 0, 0, 0);
            }
        }

        if (pre) {
            #pragma unroll
            for (int p = 0; p < 2; ++p) {
                const int rr = xs_rr[p], s16 = xs_s16[p];
                union { unsigned short us[8]; short8 v; } pk;
                pk.us[0] = f2bf(xa[p].x); pk.us[1] = f2bf(xa[p].y);
                pk.us[2] = f2bf(xa[p].z); pk.us[3] = f2bf(xa[p].w);
                pk.us[4] = f2bf(xb[p].x); pk.us[5] = f2bf(xb[p].y);
                pk.us[6] = f2bf(xb[p].z); pk.us[7] = f2bf(xb[p].w);
                const int cb = (s16 * 16) ^ ((rr & 7) << 4);
                *reinterpret_cast<short8*>((char*)(&Xs[cur ^ 1][0]) + rr * 128 + cb) = pk.v;
            }
        }
        __syncthreads();
    }

    #pragma unroll
    for (int nt = 0; nt < 3; ++nt) {
        const int gc  = cbase + nt * 32 + r;
        const int seg = gc >> 6;
        const int h   = gc & 63;
        #pragma unroll
        for (int reg = 0; reg < 16; ++reg) {
            const int drow = (reg & 3) + 8 * (reg >> 2) + 4 * hi;
            const int grow = row0 + (wid >> 1) * 32 + drow;
            const float val = acc[nt][reg];
            const int bb  = grow >> 9;
            const int key = grow & 511;
            const int blk = key >> 5;
            const int kk  = key & 31;
            if (seg == 0) {
                qfrag[(((size_t)bb * 16 + blk) * 4 + (h >> 4)) * 512
                      + (((h >> 3) & 1) * 32 + kk) * 8 + (h & 7)] = f2bf(val * QSCALE);
            } else if (seg == 1) {
                kfrag[(((size_t)bb * 16 + blk) * 4 + (h >> 4)) * 512
                      + (((h >> 3) & 1) * 32 + kk) * 8 + (h & 7)] = f2bf(val);
            } else {
                vfrag[(((size_t)bb * 16 + blk) * 4 + ((kk >> 4) * 2 + (h >> 5))) * 512
                      + (((kk >> 3) & 1) * 32 + (h & 31)) * 8 + (kk & 7)] = f2bf(val);
            }
        }
    }
}

// ---------------------------------------------------------------------------
// Kernel 2: flash attention with INTRA-BLOCK split-K.  Block = (batch,
// 32-row strip), 4 waves; wave w handles key-blocks j == w (mod 4), keeping
// its own online (m,l,O).  Longest serial chain: 16 -> 4 iterations.  LDS
// merge (stride-68 pad, <=2-way conflicts) + coalesced normalized stores.
// ---------------------------------------------------------------------------
__global__ __launch_bounds__(256) void attn_online(
    const unsigned short* __restrict__ qfrag,
    const unsigned short* __restrict__ kfrag,
    const unsigned short* __restrict__ vfrag,
    const unsigned int* __restrict__ mbits,
    float* __restrict__ out)
{
    __shared__ float mlS[4][2][32];
    __shared__ float Ob[4][32][68];      // padded: 34.8 KB

    const int tid  = threadIdx.x;
    const int w    = tid >> 6;
    const int lane = tid & 63;
    const int hi = lane >> 5, r = lane & 31;
    const int h4 = 4 * hi;

    // XCD packing: all 16 strips of a batch on one XCD
    const int bid = blockIdx.x;
    const int kk2 = bid >> 3;
    const int b   = ((kk2 >> 4) << 3) | (bid & 7);
    const int s   = 15 - (kk2 & 15);
    const int t0  = s * 32;
    const int tq  = t0 + r;
    const int l8  = lane * 8;

    f32x16 accO[2] = {};
    float m = -INFINITY, l = 0.f;

    if (w <= s) {
        // Q fragments (QSCALE folded)
        short8 qf[4];
        {
            const unsigned short* qb = qfrag + (((size_t)b * 16 + s) * 4) * 512;
            #pragma unroll
            for (int ks = 0; ks < 4; ++ks)
                qf[ks] = *reinterpret_cast<const short8*>(qb + ks * 512 + l8);
        }
        // prologue: K/V for first block j0 = w
        short8 kf[4], vb[4];
        {
            const unsigned short* kb = kfrag + (((size_t)b * 16 + w) * 4) * 512;
            const unsigned short* vv = vfrag + (((size_t)b * 16 + w) * 4) * 512;
            #pragma unroll
            for (int ks = 0; ks < 4; ++ks) {
                kf[ks] = *reinterpret_cast<const short8*>(kb + ks * 512 + l8);
                vb[ks] = *reinterpret_cast<const short8*>(vv + ks * 512 + l8);
            }
        }

        for (int j = w; j <= s; j += 4) {
            // prefetch next block for this wave
            short8 kn[4], vn[4];
            if (j + 4 <= s) {
                const unsigned short* kb = kfrag + (((size_t)b * 16 + j + 4) * 4) * 512;
                const unsigned short* vv = vfrag + (((size_t)b * 16 + j + 4) * 4) * 512;
                #pragma unroll
                for (int ks = 0; ks < 4; ++ks) {
                    kn[ks] = *reinterpret_cast<const short8*>(kb + ks * 512 + l8);
                    vn[ks] = *reinterpret_cast<const short8*>(vv + ks * 512 + l8);
                }
            }

            f32x16 sc = {};
            #pragma unroll
            for (int ks = 0; ks < 4; ++ks)
                sc = __builtin_amdgcn_mfma_f32_32x32x16_bf16(kf[ks], qf[ks], sc, 0, 0, 0);

            const unsigned int mw = mbits[b * 16 + j];
            const bool fullm = (mw == 0xffffffffu);
            float cmax = -INFINITY;
            if (j == s) {          // diagonal: causal (+ bits if partial mask)
                #pragma unroll
                for (int reg = 0; reg < 16; ++reg) {
                    const int cr = (reg & 3) + 8 * (reg >> 2) + h4;
                    float v = sc[reg];
                    const bool bad = (32 * j + cr > tq) || (!fullm && !((mw >> cr) & 1u));
                    v = bad ? NEG_INF : v;
                    sc[reg] = v;
                    cmax = fmaxf(cmax, v);
                }
            } else if (fullm) {    // fast path: no masking at all
                #pragma unroll
                for (int reg = 0; reg < 16; ++reg)
                    cmax = fmaxf(cmax, sc[reg]);
            } else {
                #pragma unroll
                for (int reg = 0; reg < 16; ++reg) {
                    const int cr = (reg & 3) + 8 * (reg >> 2) + h4;
                    float v = sc[reg];
                    v = ((mw >> cr) & 1u) ? v : NEG_INF;
                    sc[reg] = v;
                    cmax = fmaxf(cmax, v);
                }
            }
            cmax = fmaxf(cmax, __shfl_xor(cmax, 32));

            if (!__all(cmax <= m + DEFER_THR)) {
                const float m_new = fmaxf(m, cmax);
                const float scale = exp2f(m - m_new);
                f32x16 scf;
                #pragma unroll
                for (int reg = 0; reg < 16; ++reg)
                    scf[reg] = __shfl(scale, (reg & 3) + 8 * (reg >> 2) + h4);
                #pragma unroll
                for (int reg = 0; reg < 16; ++reg) {
                    accO[0][reg] *= scf[reg];
                    accO[1][reg] *= scf[reg];
                }
                l *= scale;
                m = m_new;
            }

            float csum = 0.f;
            #pragma unroll
            for (int reg = 0; reg < 16; ++reg) {
                const float p = exp2f(sc[reg] - m);
                sc[reg] = p;
                csum += p;
            }
            csum += __shfl_xor(csum, 32);
            l += csum;

            unsigned int pk[8];
            #pragma unroll
            for (int jj = 0; jj < 8; ++jj)
                pk[jj] = bfpack_tr(sc[2 * jj], sc[2 * jj + 1]);
            #pragma unroll
            for (int hs = 0; hs < 2; ++hs) {
                const unsigned int p01 = pk[hs * 4 + 0], p23 = pk[hs * 4 + 1];
                const unsigned int p45 = pk[hs * 4 + 2], p67 = pk[hs * 4 + 3];
                const unsigned int sendA = hi ? p01 : p45;
                const unsigned int sendB = hi ? p23 : p67;
                const unsigned int recvA = (unsigned int)__shfl_xor((int)sendA, 32);
                const unsigned int recvB = (unsigned int)__shfl_xor((int)sendB, 32);
                union { unsigned int uu[4]; short8 s8; } aw;
                aw.uu[0] = hi ? recvA : p01;
                aw.uu[1] = hi ? recvB : p23;
                aw.uu[2] = hi ? p45 : recvA;
                aw.uu[3] = hi ? p67 : recvB;
                #pragma unroll
                for (int tile = 0; tile < 2; ++tile)
                    accO[tile] = __builtin_amdgcn_mfma_f32_32x32x16_bf16(
                        aw.s8, vb[hs * 2 + tile], accO[tile], 0, 0, 0);
            }

            #pragma unroll
            for (int ks = 0; ks < 4; ++ks) { kf[ks] = kn[ks]; vb[ks] = vn[ks]; }
        }
    }

    // ---- write per-wave partials to LDS ----
    if (hi == 0) { mlS[w][0][r] = m; mlS[w][1][r] = l; }
    #pragma unroll
    for (int reg = 0; reg < 16; ++reg) {
        const int qrow = (reg & 3) + 8 * (reg >> 2) + h4;
        Ob[w][qrow][r]      = accO[0][reg];
        Ob[w][qrow][r + 32] = accO[1][reg];
    }
    __syncthreads();

    // ---- merge 4 partials, normalize, store ----
    {
        const int row = tid >> 3;
        const int c8  = (tid & 7) * 8;

        float mi[4], li[4];
        float mstar = -INFINITY;
        #pragma unroll
        for (int w2 = 0; w2 < 4; ++w2) {
            mi[w2] = mlS[w2][0][row];
            li[w2] = mlS[w2][1][row];
            mstar = fmaxf(mstar, mi[w2]);
        }
        float L = 0.f, fw[4];
        #pragma unroll
        for (int w2 = 0; w2 < 4; ++w2) {
            fw[w2] = exp2f(mi[w2] - mstar);     // exp2(-inf)=0 for idle waves
            L += fw[w2] * li[w2];
        }
        const float inv = 1.f / L;

        float acc[8] = {};
        #pragma unroll
        for (int w2 = 0; w2 < 4; ++w2) {
            const float4 lo = *reinterpret_cast<const float4*>(&Ob[w2][row][c8]);
            const float4 hi4v = *reinterpret_cast<const float4*>(&Ob[w2][row][c8 + 4]);
            acc[0] += fw[w2] * lo.x;  acc[1] += fw[w2] * lo.y;
            acc[2] += fw[w2] * lo.z;  acc[3] += fw[w2] * lo.w;
            acc[4] += fw[w2] * hi4v.x; acc[5] += fw[w2] * hi4v.y;
            acc[6] += fw[w2] * hi4v.z; acc[7] += fw[w2] * hi4v.w;
        }

        float* op = &out[((size_t)b * T + t0 + row) * H + c8];
        float4 o0 = { acc[0] * inv, acc[1] * inv, acc[2] * inv, acc[3] * inv };
        float4 o1 = { acc[4] * inv, acc[5] * inv, acc[6] * inv, acc[7] * inv };
        *reinterpret_cast<float4*>(op)     = o0;
        *reinterpret_cast<float4*>(op + 4) = o1;
    }
}

// ---------------------------------------------------------------------------
extern "C" void kernel_launch(void* const* d_in, const int* in_sizes, int n_in,
                              void* d_out, int out_size, void* d_ws, size_t ws_size,
                              hipStream_t stream) {
    const float* x         = (const float*)d_in[0];
    const int*   attn_mask = (const int*)d_in[1];
    const float* Wk        = (const float*)d_in[2];
    const float* Wq        = (const float*)d_in[3];
    const float* Wv        = (const float*)d_in[4];
    float* out = (float*)d_out;

    unsigned short* qfrag  = (unsigned short*)d_ws;                      // 4 MB
    unsigned short* kfrag  = qfrag + (size_t)B * T * H;                  // 4 MB
    unsigned short* vfrag  = kfrag + (size_t)B * T * H;                  // 4 MB
    unsigned short* WT_swz = vfrag + (size_t)B * T * H;                  // 192 KB
    unsigned int*   mbits  = (unsigned int*)(WT_swz + (size_t)PN * E);   // 4 KB

    prep<<<512, 256, 0, stream>>>(Wq, Wk, Wv, attn_mask, WT_swz, mbits);
    proj_gemm<<<(B * T) / PBM, 256, 0, stream>>>(x, WT_swz, qfrag, kfrag, vfrag);
    attn_online<<<B * 16, 256, 0, stream>>>(qfrag, kfrag, vfrag, mbits, out);
}

// Round 13
// 45.269 us; speedup vs baseline: 1.2968x; 1.0633x over previous
//
#include <hip/hip_runtime.h>

#define B 64
#define T 512
#define E 512
#define H 64
#define NEG_INF (-1e30f)

// ---------------- projection GEMM params ----------------
#define PBM 64
#define PBK 64
#define PN 192
#define NCHK (E / PBK)

// q pre-scale: H^-0.5 * log2(e)  (scores land in log2 domain)
#define QSCALE 0.18033688011112043f
#define DEFER_THR 8.0f

using short8 = __attribute__((ext_vector_type(8))) short;
using f32x16 = __attribute__((ext_vector_type(16))) float;

__device__ __forceinline__ unsigned short f2bf(float f) {
    unsigned int u = __float_as_uint(f);
    u += 0x7fffu + ((u >> 16) & 1u);
    return (unsigned short)(u >> 16);
}
__device__ __forceinline__ unsigned int bfpack_tr(float lo, float hi) {
    return (__float_as_uint(hi) & 0xffff0000u) | (__float_as_uint(lo) >> 16);
}
__device__ __forceinline__ void async_copy16(const void* g, void* l) {
    __builtin_amdgcn_global_load_lds(
        (const __attribute__((address_space(1))) unsigned int*)g,
        (__attribute__((address_space(3))) unsigned int*)l, 16, 0, 0);
}

// counted waits (rule #18: sched_barrier after inline-asm waitcnt)
#define WAIT_VM16() do { asm volatile("s_waitcnt vmcnt(16)" ::: "memory"); \
                         __builtin_amdgcn_sched_barrier(0); } while (0)
#define WAIT_VM0()  do { asm volatile("s_waitcnt vmcnt(0)"  ::: "memory"); \
                         __builtin_amdgcn_sched_barrier(0); } while (0)
#define LGKM_BARRIER() do { asm volatile("s_waitcnt lgkmcnt(0)" ::: "memory"); \
                            __builtin_amdgcn_s_barrier(); \
                            __builtin_amdgcn_sched_barrier(0); } while (0)

// ---------------------------------------------------------------------------
// Kernel 0: one-time prep (unchanged).
// ---------------------------------------------------------------------------
__global__ __launch_bounds__(256) void prep(
    const float* __restrict__ Wq, const float* __restrict__ Wk,
    const float* __restrict__ Wv, const int* __restrict__ am,
    unsigned short* __restrict__ WT_swz, unsigned int* __restrict__ mbits)
{
    const int bid = blockIdx.x;
    if (bid < 384) {
        const int i = bid * 256 + threadIdx.x;
        const int c   = i / (PN * 64);
        const int rem = i - c * (PN * 64);
        const int row = rem >> 6;
        const int s   = rem & 63;
        const int klocal = s ^ ((row & 7) << 3);
        const int k   = c * 64 + klocal;
        const int seg = row >> 6, hh = row & 63;
        const float* W = (seg == 0) ? Wq : (seg == 1) ? Wk : Wv;
        WT_swz[i] = f2bf(W[(size_t)k * H + hh]);
    } else {
        const int i = (bid - 384) * 256 + threadIdx.x;
        const unsigned long long bal = __ballot(am[i] != 0);
        const int lane = threadIdx.x & 63;
        if (lane == 0)       mbits[i >> 5] = (unsigned int)bal;
        else if (lane == 32) mbits[i >> 5] = (unsigned int)(bal >> 32);
    }
}

// ---------------------------------------------------------------------------
// Kernel 1: projection GEMM with BARRIER-DRAIN-FREE K-loop.
// - W staging is wave-private: each wave stages its own col-half (12
//   global_load_lds; the 2 waves per half write duplicate identical data),
//   so W readiness needs only the wave's OWN counted vmcnt, not a barrier.
// - Per iter: issue W(c+1) (+12) and x(c+2) (+4, 2-deep), s_waitcnt
//   vmcnt(16) before MFMAs -> prefetches stay in flight ACROSS the barrier.
// - Cross-wave Xs handled by raw lgkmcnt(0)+s_barrier (no vmcnt drain).
// Epilogue: fragment-layout scatter (unchanged).
// ---------------------------------------------------------------------------
__global__ __launch_bounds__(256) void proj_gemm(
    const float* __restrict__ x,
    const unsigned short* __restrict__ WT_swz,
    unsigned short* __restrict__ qfrag, unsigned short* __restrict__ kfrag,
    unsigned short* __restrict__ vfrag)
{
    __shared__ unsigned short Xs[2][PBM * 64];   // 2 x 8 KB
    __shared__ unsigned short Ws[2][PN * 64];    // 2 x 24 KB

    const int tid  = threadIdx.x;
    const int wid  = tid >> 6;
    const int lane = tid & 63;
    const int hi   = lane >> 5;
    const int r    = lane & 31;
    const int row0 = blockIdx.x * PBM;

    const int mrow  = (wid >> 1) * 32 + r;
    const int hhalf = wid & 1;                 // wave's column half
    const int cbase = hhalf * 96;

    const int aBase = mrow * 128;
    const int aXor  = (mrow & 7) << 4;
    int bBase[3], bXor[3];
    #pragma unroll
    for (int nt = 0; nt < 3; ++nt) {
        const int col = cbase + nt * 32 + r;
        bBase[nt] = col * 128;
        bXor[nt]  = (col & 7) << 4;
    }
    const int xs_rr[2]  = { tid >> 3, (256 + tid) >> 3 };
    const int xs_s16    = tid & 7;

    // wave-private W staging coords: half = 96 rows x 64 shorts = 768 granules
    const unsigned short* wsrcbase = WT_swz + hhalf * 6144 + lane * 8;
    const int wdst = hhalf * 12288;            // byte offset within Ws buffer

    f32x16 acc[3] = {};
    float4 xA[2][2], xB[2][2];                 // x staging banks [k&1][granule]

    // ---- prologue ----
    {
        // issue W(0) (wave-private half, 12 copies)
        #pragma unroll
        for (int p = 0; p < 12; ++p)
            async_copy16(wsrcbase + p * 512,
                         (char*)(&Ws[0][0]) + wdst + p * 1024);
        // x(0): load, convert, write (one-time stall)
        #pragma unroll
        for (int p = 0; p < 2; ++p) {
            const float4* src = reinterpret_cast<const float4*>(
                &x[(size_t)(row0 + xs_rr[p]) * E + xs_s16 * 8]);
            const float4 a0 = src[0], a1 = src[1];
            union { unsigned short us[8]; short8 v; } pk;
            pk.us[0] = f2bf(a0.x); pk.us[1] = f2bf(a0.y);
            pk.us[2] = f2bf(a0.z); pk.us[3] = f2bf(a0.w);
            pk.us[4] = f2bf(a1.x); pk.us[5] = f2bf(a1.y);
            pk.us[6] = f2bf(a1.z); pk.us[7] = f2bf(a1.w);
            const int cb = (xs_s16 * 16) ^ ((xs_rr[p] & 7) << 4);
            *reinterpret_cast<short8*>((char*)(&Xs[0][0]) + xs_rr[p] * 128 + cb) = pk.v;
        }
        // issue x(1) into bank 1
        #pragma unroll
        for (int p = 0; p < 2; ++p) {
            const float4* src = reinterpret_cast<const float4*>(
                &x[(size_t)(row0 + xs_rr[p]) * E + PBK + xs_s16 * 8]);
            xA[1][p] = src[0];
            xB[1][p] = src[1];
        }
        LGKM_BARRIER();
    }

    #pragma unroll
    for (int c = 0; c < NCHK; ++c) {
        const int cur = c & 1;

        // issue W(c+1) into other buffer (wave-private)
        if (c + 1 < NCHK) {
            const unsigned short* gw = wsrcbase + (size_t)(c + 1) * (PN * 64);
            #pragma unroll
            for (int p = 0; p < 12; ++p)
                async_copy16(gw + p * 512,
                             (char*)(&Ws[cur ^ 1][0]) + wdst + p * 1024);
        }
        // issue x(c+2) into bank c&1 (2-deep prefetch)
        if (c + 2 < NCHK) {
            const int kc = (c + 2) * PBK;
            #pragma unroll
            for (int p = 0; p < 2; ++p) {
                const float4* src = reinterpret_cast<const float4*>(
                    &x[(size_t)(row0 + xs_rr[p]) * E + kc + xs_s16 * 8]);
                xA[cur][p] = src[0];
                xB[cur][p] = src[1];
            }
        }

        // wait for W(c) (oldest 12) + x(c+1); keep W(c+1)+x(c+2) in flight
        if (c == NCHK - 1) { WAIT_VM0(); } else { WAIT_VM16(); }

        // ---- 12 MFMAs on buffer cur ----
        #pragma unroll
        for (int ks = 0; ks < 4; ++ks) {
            const int koff = ks * 32 + hi * 16;
            const short8 a = *reinterpret_cast<const short8*>(
                (const char*)(&Xs[cur][0]) + aBase + (koff ^ aXor));
            #pragma unroll
            for (int nt = 0; nt < 3; ++nt) {
                const short8 b = *reinterpret_cast<const short8*>(
                    (const char*)(&Ws[cur][0]) + bBase[nt] + (koff ^ bXor[nt]));
                acc[nt] = __builtin_amdgcn_mfma_f32_32x32x16_bf16(a, b, acc[nt], 0, 0, 0);
            }
        }

        // convert + write Xs(c+1) from bank (c+1)&1, then cheap barrier
        if (c + 1 < NCHK) {
            const int nb = (c + 1) & 1;
            #pragma unroll
            for (int p = 0; p < 2; ++p) {
                union { unsigned short us[8]; short8 v; } pk;
                pk.us[0] = f2bf(xA[nb][p].x); pk.us[1] = f2bf(xA[nb][p].y);
                pk.us[2] = f2bf(xA[nb][p].z); pk.us[3] = f2bf(xA[nb][p].w);
                pk.us[4] = f2bf(xB[nb][p].x); pk.us[5] = f2bf(xB[nb][p].y);
                pk.us[6] = f2bf(xB[nb][p].z); pk.us[7] = f2bf(xB[nb][p].w);
                const int cb = (xs_s16 * 16) ^ ((xs_rr[p] & 7) << 4);
                *reinterpret_cast<short8*>(
                    (char*)(&Xs[cur ^ 1][0]) + xs_rr[p] * 128 + cb) = pk.v;
            }
            LGKM_BARRIER();
        }
    }

    // ---- epilogue: scatter into fragment layouts (unchanged) ----
    #pragma unroll
    for (int nt = 0; nt < 3; ++nt) {
        const int gc  = cbase + nt * 32 + r;
        const int seg = gc >> 6;
        const int h   = gc & 63;
        #pragma unroll
        for (int reg = 0; reg < 16; ++reg) {
            const int drow = (reg & 3) + 8 * (reg >> 2) + 4 * hi;
            const int grow = row0 + (wid >> 1) * 32 + drow;
            const float val = acc[nt][reg];
            const int bb  = grow >> 9;
            const int key = grow & 511;
            const int blk = key >> 5;
            const int kk  = key & 31;
            if (seg == 0) {
                qfrag[(((size_t)bb * 16 + blk) * 4 + (h >> 4)) * 512
                      + (((h >> 3) & 1) * 32 + kk) * 8 + (h & 7)] = f2bf(val * QSCALE);
            } else if (seg == 1) {
                kfrag[(((size_t)bb * 16 + blk) * 4 + (h >> 4)) * 512
                      + (((h >> 3) & 1) * 32 + kk) * 8 + (h & 7)] = f2bf(val);
            } else {
                vfrag[(((size_t)bb * 16 + blk) * 4 + ((kk >> 4) * 2 + (h >> 5))) * 512
                      + (((kk >> 3) & 1) * 32 + (h & 31)) * 8 + (kk & 7)] = f2bf(val);
            }
        }
    }
}

// ---------------------------------------------------------------------------
// Kernel 2: flash attention with intra-block split-K (R12, unchanged).
// ---------------------------------------------------------------------------
__global__ __launch_bounds__(256) void attn_online(
    const unsigned short* __restrict__ qfrag,
    const unsigned short* __restrict__ kfrag,
    const unsigned short* __restrict__ vfrag,
    const unsigned int* __restrict__ mbits,
    float* __restrict__ out)
{
    __shared__ float mlS[4][2][32];
    __shared__ float Ob[4][32][68];

    const int tid  = threadIdx.x;
    const int w    = tid >> 6;
    const int lane = tid & 63;
    const int hi = lane >> 5, r = lane & 31;
    const int h4 = 4 * hi;

    const int bid = blockIdx.x;
    const int kk2 = bid >> 3;
    const int b   = ((kk2 >> 4) << 3) | (bid & 7);
    const int s   = 15 - (kk2 & 15);
    const int t0  = s * 32;
    const int tq  = t0 + r;
    const int l8  = lane * 8;

    f32x16 accO[2] = {};
    float m = -INFINITY, l = 0.f;

    if (w <= s) {
        short8 qf[4];
        {
            const unsigned short* qb = qfrag + (((size_t)b * 16 + s) * 4) * 512;
            #pragma unroll
            for (int ks = 0; ks < 4; ++ks)
                qf[ks] = *reinterpret_cast<const short8*>(qb + ks * 512 + l8);
        }
        short8 kf[4], vb[4];
        {
            const unsigned short* kb = kfrag + (((size_t)b * 16 + w) * 4) * 512;
            const unsigned short* vv = vfrag + (((size_t)b * 16 + w) * 4) * 512;
            #pragma unroll
            for (int ks = 0; ks < 4; ++ks) {
                kf[ks] = *reinterpret_cast<const short8*>(kb + ks * 512 + l8);
                vb[ks] = *reinterpret_cast<const short8*>(vv + ks * 512 + l8);
            }
        }

        for (int j = w; j <= s; j += 4) {
            short8 kn[4], vn[4];
            if (j + 4 <= s) {
                const unsigned short* kb = kfrag + (((size_t)b * 16 + j + 4) * 4) * 512;
                const unsigned short* vv = vfrag + (((size_t)b * 16 + j + 4) * 4) * 512;
                #pragma unroll
                for (int ks = 0; ks < 4; ++ks) {
                    kn[ks] = *reinterpret_cast<const short8*>(kb + ks * 512 + l8);
                    vn[ks] = *reinterpret_cast<const short8*>(vv + ks * 512 + l8);
                }
            }

            f32x16 sc = {};
            #pragma unroll
            for (int ks = 0; ks < 4; ++ks)
                sc = __builtin_amdgcn_mfma_f32_32x32x16_bf16(kf[ks], qf[ks], sc, 0, 0, 0);

            const unsigned int mw = mbits[b * 16 + j];
            const bool fullm = (mw == 0xffffffffu);
            float cmax = -INFINITY;
            if (j == s) {
                #pragma unroll
                for (int reg = 0; reg < 16; ++reg) {
                    const int cr = (reg & 3) + 8 * (reg >> 2) + h4;
                    float v = sc[reg];
                    const bool bad = (32 * j + cr > tq) || (!fullm && !((mw >> cr) & 1u));
                    v = bad ? NEG_INF : v;
                    sc[reg] = v;
                    cmax = fmaxf(cmax, v);
                }
            } else if (fullm) {
                #pragma unroll
                for (int reg = 0; reg < 16; ++reg)
                    cmax = fmaxf(cmax, sc[reg]);
            } else {
                #pragma unroll
                for (int reg = 0; reg < 16; ++reg) {
                    const int cr = (reg & 3) + 8 * (reg >> 2) + h4;
                    float v = sc[reg];
                    v = ((mw >> cr) & 1u) ? v : NEG_INF;
                    sc[reg] = v;
                    cmax = fmaxf(cmax, v);
                }
            }
            cmax = fmaxf(cmax, __shfl_xor(cmax, 32));

            if (!__all(cmax <= m + DEFER_THR)) {
                const float m_new = fmaxf(m, cmax);
                const float scale = exp2f(m - m_new);
                f32x16 scf;
                #pragma unroll
                for (int reg = 0; reg < 16; ++reg)
                    scf[reg] = __shfl(scale, (reg & 3) + 8 * (reg >> 2) + h4);
                #pragma unroll
                for (int reg = 0; reg < 16; ++reg) {
                    accO[0][reg] *= scf[reg];
                    accO[1][reg] *= scf[reg];
                }
                l *= scale;
                m = m_new;
            }

            float csum = 0.f;
            #pragma unroll
            for (int reg = 0; reg < 16; ++reg) {
                const float p = exp2f(sc[reg] - m);
                sc[reg] = p;
                csum += p;
            }
            csum += __shfl_xor(csum, 32);
            l += csum;

            unsigned int pk[8];
            #pragma unroll
            for (int jj = 0; jj < 8; ++jj)
                pk[jj] = bfpack_tr(sc[2 * jj], sc[2 * jj + 1]);
            #pragma unroll
            for (int hs = 0; hs < 2; ++hs) {
                const unsigned int p01 = pk[hs * 4 + 0], p23 = pk[hs * 4 + 1];
                const unsigned int p45 = pk[hs * 4 + 2], p67 = pk[hs * 4 + 3];
                const unsigned int sendA = hi ? p01 : p45;
                const unsigned int sendB = hi ? p23 : p67;
                const unsigned int recvA = (unsigned int)__shfl_xor((int)sendA, 32);
                const unsigned int recvB = (unsigned int)__shfl_xor((int)sendB, 32);
                union { unsigned int uu[4]; short8 s8; } aw;
                aw.uu[0] = hi ? recvA : p01;
                aw.uu[1] = hi ? recvB : p23;
                aw.uu[2] = hi ? p45 : recvA;
                aw.uu[3] = hi ? p67 : recvB;
                #pragma unroll
                for (int tile = 0; tile < 2; ++tile)
                    accO[tile] = __builtin_amdgcn_mfma_f32_32x32x16_bf16(
                        aw.s8, vb[hs * 2 + tile], accO[tile], 0, 0, 0);
            }

            #pragma unroll
            for (int ks = 0; ks < 4; ++ks) { kf[ks] = kn[ks]; vb[ks] = vn[ks]; }
        }
    }

    if (hi == 0) { mlS[w][0][r] = m; mlS[w][1][r] = l; }
    #pragma unroll
    for (int reg = 0; reg < 16; ++reg) {
        const int qrow = (reg & 3) + 8 * (reg >> 2) + h4;
        Ob[w][qrow][r]      = accO[0][reg];
        Ob[w][qrow][r + 32] = accO[1][reg];
    }
    __syncthreads();

    {
        const int row = tid >> 3;
        const int c8  = (tid & 7) * 8;

        float mi[4], li[4];
        float mstar = -INFINITY;
        #pragma unroll
        for (int w2 = 0; w2 < 4; ++w2) {
            mi[w2] = mlS[w2][0][row];
            li[w2] = mlS[w2][1][row];
            mstar = fmaxf(mstar, mi[w2]);
        }
        float L = 0.f, fw[4];
        #pragma unroll
        for (int w2 = 0; w2 < 4; ++w2) {
            fw[w2] = exp2f(mi[w2] - mstar);
            L += fw[w2] * li[w2];
        }
        const float inv = 1.f / L;

        float acc[8] = {};
        #pragma unroll
        for (int w2 = 0; w2 < 4; ++w2) {
            const float4 lo = *reinterpret_cast<const float4*>(&Ob[w2][row][c8]);
            const float4 hi4v = *reinterpret_cast<const float4*>(&Ob[w2][row][c8 + 4]);
            acc[0] += fw[w2] * lo.x;  acc[1] += fw[w2] * lo.y;
            acc[2] += fw[w2] * lo.z;  acc[3] += fw[w2] * lo.w;
            acc[4] += fw[w2] * hi4v.x; acc[5] += fw[w2] * hi4v.y;
            acc[6] += fw[w2] * hi4v.z; acc[7] += fw[w2] * hi4v.w;
        }

        float* op = &out[((size_t)b * T + t0 + row) * H + c8];
        float4 o0 = { acc[0] * inv, acc[1] * inv, acc[2] * inv, acc[3] * inv };
        float4 o1 = { acc[4] * inv, acc[5] * inv, acc[6] * inv, acc[7] * inv };
        *reinterpret_cast<float4*>(op)     = o0;
        *reinterpret_cast<float4*>(op + 4) = o1;
    }
}

// ---------------------------------------------------------------------------
extern "C" void kernel_launch(void* const* d_in, const int* in_sizes, int n_in,
                              void* d_out, int out_size, void* d_ws, size_t ws_size,
                              hipStream_t stream) {
    const float* x         = (const float*)d_in[0];
    const int*   attn_mask = (const int*)d_in[1];
    const float* Wk        = (const float*)d_in[2];
    const float* Wq        = (const float*)d_in[3];
    const float* Wv        = (const float*)d_in[4];
    float* out = (float*)d_out;

    unsigned short* qfrag  = (unsigned short*)d_ws;                      // 4 MB
    unsigned short* kfrag  = qfrag + (size_t)B * T * H;                  // 4 MB
    unsigned short* vfrag  = kfrag + (size_t)B * T * H;                  // 4 MB
    unsigned short* WT_swz = vfrag + (size_t)B * T * H;                  // 192 KB
    unsigned int*   mbits  = (unsigned int*)(WT_swz + (size_t)PN * E);   // 4 KB

    prep<<<512, 256, 0, stream>>>(Wq, Wk, Wv, attn_mask, WT_swz, mbits);
    proj_gemm<<<(B * T) / PBM, 256, 0, stream>>>(x, WT_swz, qfrag, kfrag, vfrag);
    attn_online<<<B * 16, 256, 0, stream>>>(qfrag, kfrag, vfrag, mbits, out);
}